// Round 9
// baseline (79.417 us; speedup 1.0000x reference)
//
#include <hip/hip_runtime.h>

typedef unsigned short u16;
typedef unsigned int u32;
typedef __attribute__((ext_vector_type(8))) short bf16x8;
typedef __attribute__((ext_vector_type(4))) float f32x4;
typedef __attribute__((ext_vector_type(4))) unsigned short u16x4;

#define DEVI __device__ __forceinline__
#define AS1 __attribute__((address_space(1)))
#define AS3 __attribute__((address_space(3)))

constexpr float L2GAMMA = -0.15200309344504997f; // log2(0.9)
constexpr float INV_SQRT_H = 0.0625f;            // 1/sqrt(256)

DEVI u16 f2bf(float x) {
  union { float f; unsigned u; } v; v.f = x;
  unsigned r = v.u + 0x7FFFu + ((v.u >> 16) & 1u);
  return (u16)(r >> 16);
}

DEVI u32 pack2bf(float f0, float f1) {
  u32 u0 = __float_as_uint(f0) + 0x8000u;
  u32 u1 = __float_as_uint(f1) + 0x8000u;
  return __builtin_amdgcn_perm(u1, u0, 0x07060302u); // [f1.hi16 : f0.hi16]
}

// ---- kernel 0: W_Q|W_K|W_V (each 256x1024 fp32) -> Wb[768][1024] bf16 ----
__global__ void cvt_w_kernel(const float4* __restrict__ wq, const float4* __restrict__ wk,
                             const float4* __restrict__ wv, u16x4* __restrict__ dst) {
  int i = blockIdx.x * blockDim.x + threadIdx.x; // 0..196607
  int w = i >> 16, off = i & 65535;
  const float4* s = (w == 0) ? wq : ((w == 1) ? wk : wv);
  float4 v = s[off];
  u16x4 o; o.x = f2bf(v.x); o.y = f2bf(v.y); o.z = f2bf(v.z); o.w = f2bf(v.w);
  dst[(w << 16) + off] = o;
}

// ---- kernel 1: fused QKV GEMM  C[16384x768] = x[16384x1024](fp32)*Wb^T ---
// Phased counted-vmcnt template (T3+T4+T5+T2) at BM=256 BN=192 BK=64,
// 512 thr (8 waves 2Mx4N, wave out 128x48), grid 256 = 1 WG/CU.
// LDS 136KB: A dbuf 2x32KB (bf16, fused fp32->bf16 cvt in regs, ds_write),
//            B 3-buf rotation 3x24KB (gload_lds, pre-swizzled global src).
// Per tile t: issue A(t+1)->regs FIRST, then B(t+2) gload_lds (issue order
// makes the compiler's reg-wait on A-cvt prove B(t+1) landed while B(t+2)
// flies on); {frag-read,24 MFMA} x2 clusters with cvt+ds_write between;
// end: vmcnt(3) lgkmcnt(0) + raw s_barrier (never vmcnt(0) mid-loop).
// Swizzle: 128B rows, 8x16B slots, phys = slot ^ (row&7); all reads/writes
// <=2-way per quarter-wave.
__global__ __launch_bounds__(512, 2) void qkv_gemm_kernel(const float* __restrict__ Xf, const u16* __restrict__ Wb,
                                                          u16* __restrict__ Qb, u16* __restrict__ Kb,
                                                          u16* __restrict__ Vt) {
  __shared__ u16 Al[2][256 * 64];   // 2 x 32 KB
  __shared__ u16 Bl[3][192 * 64];   // 3 x 24 KB
  const int bid = blockIdx.x;       // 0..255
  const int xcd = bid & 7, seq = bid >> 3;
  const int m0 = (xcd * 8 + (seq >> 2)) * 256;
  const int n0 = (seq & 3) * 192;
  const int tid = threadIdx.x;
  const int wid = tid >> 6, lane = tid & 63;
  const int wm = wid >> 2, wn = wid & 3;   // 2M x 4N
  const int lrow = lane & 15, lkg = lane >> 4;

  // A load map: round j (0..7): row = j*32 + (tid>>4), fp32 16B-slot = tid&15
  const int a_r = tid >> 4, a_s = tid & 15;
  const float* a_g = Xf + (size_t)(m0 + a_r) * 1024 + a_s * 4;
  const int a_wr = a_r * 64 + (((a_s >> 1) ^ (a_r & 7)) << 3) + ((a_s & 1) << 2); // u16 idx, row part added per j
  // B stage map: round j (0..2): row = j*64 + (tid>>3), phys slot = tid&7 (linear dest)
  const int b_r = tid >> 3;
  const u16* b_g = Wb + (size_t)(n0 + b_r) * 1024 + (((tid & 7) ^ (b_r & 7)) << 3);

  float4 ar[8];

#define ALOAD(T) do { const float* g_ = a_g + (T) * 64; \
  _Pragma("unroll") for (int j_ = 0; j_ < 8; ++j_) \
    ar[j_] = *(const float4*)(g_ + (size_t)j_ * 32 * 1024); } while (0)

#define ACVT(P) do { \
  _Pragma("unroll") for (int j_ = 0; j_ < 8; ++j_) { \
    uint2 pk_; pk_.x = pack2bf(ar[j_].x, ar[j_].y); pk_.y = pack2bf(ar[j_].z, ar[j_].w); \
    *(uint2*)&Al[P][j_ * 2048 + a_wr] = pk_; } } while (0)

#define BSTAGE(T, BUF) do { const u16* g_ = b_g + (T) * 64; \
  _Pragma("unroll") for (int j_ = 0; j_ < 3; ++j_) \
    __builtin_amdgcn_global_load_lds((const AS1 void*)(g_ + (size_t)j_ * 64 * 1024), \
        (AS3 void*)&Bl[BUF][j_ * 4096 + tid * 8], 16, 0, 0); } while (0)

#define KKSTEP(KK, P, BQ) do { bf16x8 af_[8], bf_[3]; \
  const int ps_ = (((KK) * 4 + lkg) ^ (lrow & 7)) << 3; \
  _Pragma("unroll") for (int mf = 0; mf < 8; ++mf) \
    af_[mf] = *(const bf16x8*)&Al[P][(wm * 128 + mf * 16 + lrow) * 64 + ps_]; \
  _Pragma("unroll") for (int nf = 0; nf < 3; ++nf) \
    bf_[nf] = *(const bf16x8*)&Bl[BQ][(wn * 48 + nf * 16 + lrow) * 64 + ps_]; \
  __builtin_amdgcn_s_setprio(1); \
  _Pragma("unroll") for (int mf = 0; mf < 8; ++mf) \
    _Pragma("unroll") for (int nf = 0; nf < 3; ++nf) \
      acc[mf][nf] = __builtin_amdgcn_mfma_f32_16x16x32_bf16(af_[mf], bf_[nf], acc[mf][nf], 0, 0, 0); \
  __builtin_amdgcn_s_setprio(0); } while (0)

  f32x4 acc[8][3] = {};

  // ---- prologue ----
  ALOAD(0);                 // oldest in flight
  BSTAGE(0, 0); BSTAGE(1, 1);
  ACVT(0);                  // reg-wait drains A(0); B(0),B(1) stay outstanding
  asm volatile("s_waitcnt vmcnt(3) lgkmcnt(0)" ::: "memory");  // B(0) landed
  __builtin_amdgcn_s_barrier();

  int p = 0, bq = 0, wq = 2;
  for (int t = 0; t < 16; ++t) {
    if (t + 1 < 16) ALOAD(t + 1);        // A first (older than B(t+2))
    if (t + 2 < 16) BSTAGE(t + 2, wq);
    KKSTEP(0, p, bq);
    if (t + 1 < 16) ACVT(p ^ 1);         // auto-wait proves B(t+1) done too
    KKSTEP(1, p, bq);
    if (t < 15) {
      asm volatile("s_waitcnt vmcnt(3) lgkmcnt(0)" ::: "memory");
      __builtin_amdgcn_s_barrier();
    }
    p ^= 1;
    bq = (bq == 2) ? 0 : bq + 1;
    wq = (wq == 2) ? 0 : wq + 1;
  }

  // ---- epilogue: cols 0..255 -> Q, 256..511 -> K, 512..767 -> V^T ----
#pragma unroll
  for (int mf = 0; mf < 8; ++mf)
#pragma unroll
    for (int nf = 0; nf < 3; ++nf) {
      const int gm = m0 + wm * 128 + mf * 16 + lkg * 4;
      const int c = n0 + wn * 48 + nf * 16 + lrow;
      if (c < 512) {
        u16* Dst = (c < 256) ? Qb : Kb;
        const int cc = c & 255;
#pragma unroll
        for (int r = 0; r < 4; ++r) Dst[(size_t)(gm + r) * 256 + cc] = f2bf(acc[mf][nf][r]);
      } else {
        const int h = c - 512;
        const int bb = gm >> 12, l = gm & 4095;
        u16x4 pk;
        pk.x = f2bf(acc[mf][nf][0]); pk.y = f2bf(acc[mf][nf][1]);
        pk.z = f2bf(acc[mf][nf][2]); pk.w = f2bf(acc[mf][nf][3]);
        *(u16x4*)&Vt[((size_t)bb * 256 + h) * 4096 + l] = pk;
      }
    }
}

// ---- kernel 2: WINDOWED decay attention ----------------------------------
// gamma^320 ~ 2.5e-15 => keys older than the aligned 256..319 window are
// numerically zero in fp32. QB=32 rows/WG, KB=64, 4 waves (256 thr).
__global__ __launch_bounds__(256) void attn_kernel(const u16* __restrict__ Qb, const u16* __restrict__ Kb,
                                                   const u16* __restrict__ Vt, float* __restrict__ out) {
  __shared__ u16 Plds[32 * 72];
  const int raw = blockIdx.x;                 // 0..511
  const int aid = (raw & 7) * 64 + (raw >> 3);  // XCD-chunked
  const int b = aid >> 7;                     // 0..3
  const int qt = aid & 127;                   // 0..127
  const int qb = qt * 32;
  const int tid = threadIdx.x;
  const int wid = tid >> 6, lane = tid & 63;
  const int lrow = lane & 15, lkg = lane >> 4, lk = lkg * 8;
  const size_t bQK = (size_t)b * 4096 * 256;

  bf16x8 qf[2][8];
#pragma unroll
  for (int mf = 0; mf < 2; ++mf) {
    const u16* Qrow = Qb + bQK + (size_t)(qb + mf * 16 + lrow) * 256;
#pragma unroll
    for (int kf = 0; kf < 8; ++kf) qf[mf][kf] = *(const bf16x8*)&Qrow[kf * 32 + lk];
  }

  int kstart = qb - 256; if (kstart < 0) kstart = 0; kstart &= ~63;
  const int njt = (qb + 32 - kstart + 63) >> 6;

  f32x4 oacc[2][4] = {};

  for (int jt = 0; jt < njt; ++jt) {
    const int kb = kstart + jt * 64;
    f32x4 s[2] = {};
    const u16* Krow = Kb + bQK + (size_t)(kb + wid * 16 + lrow) * 256;
#pragma unroll
    for (int kf = 0; kf < 8; ++kf) {
      const bf16x8 kfr = *(const bf16x8*)&Krow[kf * 32 + lk];
      s[0] = __builtin_amdgcn_mfma_f32_16x16x32_bf16(qf[0][kf], kfr, s[0], 0, 0, 0);
      s[1] = __builtin_amdgcn_mfma_f32_16x16x32_bf16(qf[1][kf], kfr, s[1], 0, 0, 0);
    }
    const int kg = kb + wid * 16 + lrow;
#pragma unroll
    for (int mf = 0; mf < 2; ++mf) {
      const int qg = qb + mf * 16 + lkg * 4;
#pragma unroll
      for (int r = 0; r < 4; ++r) {
        const int d = qg + r - kg;
        const float pv = (d >= 0) ? s[mf][r] * exp2f((float)d * L2GAMMA) * INV_SQRT_H : 0.0f;
        Plds[(mf * 16 + lkg * 4 + r) * 72 + wid * 16 + lrow] = f2bf(pv);
      }
    }
    __syncthreads();
#pragma unroll
    for (int ks = 0; ks < 2; ++ks) {
      bf16x8 pa[2];
      pa[0] = *(const bf16x8*)&Plds[(lrow) * 72 + ks * 32 + lk];
      pa[1] = *(const bf16x8*)&Plds[(16 + lrow) * 72 + ks * 32 + lk];
#pragma unroll
      for (int nf = 0; nf < 4; ++nf) {
        const bf16x8 vb = *(const bf16x8*)&Vt[((size_t)b * 256 + wid * 64 + nf * 16 + lrow) * 4096 + kb + ks * 32 + lk];
        oacc[0][nf] = __builtin_amdgcn_mfma_f32_16x16x32_bf16(pa[0], vb, oacc[0][nf], 0, 0, 0);
        oacc[1][nf] = __builtin_amdgcn_mfma_f32_16x16x32_bf16(pa[1], vb, oacc[1][nf], 0, 0, 0);
      }
    }
    __syncthreads();
  }

#pragma unroll
  for (int mf = 0; mf < 2; ++mf) {
    float* obase = out + ((size_t)b * 4096 + qb + mf * 16 + lkg * 4) * 256 + wid * 64 + lrow;
#pragma unroll
    for (int nf = 0; nf < 4; ++nf)
#pragma unroll
      for (int r = 0; r < 4; ++r)
        obase[(size_t)r * 256 + nf * 16] = oacc[mf][nf][r];
  }
}

extern "C" void kernel_launch(void* const* d_in, const int* in_sizes, int n_in,
                              void* d_out, int out_size, void* d_ws, size_t ws_size,
                              hipStream_t stream) {
  const float* x  = (const float*)d_in[0];
  const float* wq = (const float*)d_in[1];
  const float* wk = (const float*)d_in[2];
  const float* wv = (const float*)d_in[3];
  float* out = (float*)d_out;
  char* ws = (char*)d_ws;
  u16* Wb = (u16*)(ws);                          //   768*1024*2 = 1,572,864
  u16* Qb = (u16*)(ws + (size_t)1572864);        // 16384*256*2  = 8,388,608
  u16* Kb = (u16*)(ws + (size_t)9961472);        //  8,388,608
  u16* Vt = (u16*)(ws + (size_t)18350080);       //  8,388,608  (end 26,738,688)

  hipLaunchKernelGGL(cvt_w_kernel, dim3(768), dim3(256), 0, stream,
                     (const float4*)wq, (const float4*)wk, (const float4*)wv, (u16x4*)Wb);
  hipLaunchKernelGGL(qkv_gemm_kernel, dim3(256), dim3(512), 0, stream, x, Wb, Qb, Kb, Vt);
  hipLaunchKernelGGL(attn_kernel, dim3(512), dim3(256), 0, stream, Qb, Kb, Vt, out);
}

// Round 10
// 76.646 us; speedup vs baseline: 1.0362x; 1.0362x over previous
//
#include <hip/hip_runtime.h>

typedef unsigned short u16;
typedef unsigned int u32;
typedef __attribute__((ext_vector_type(8))) short bf16x8;
typedef __attribute__((ext_vector_type(4))) float f32x4;
typedef __attribute__((ext_vector_type(4))) unsigned short u16x4;

#define DEVI __device__ __forceinline__

constexpr float L2GAMMA = -0.15200309344504997f; // log2(0.9)
constexpr float INV_SQRT_H = 0.0625f;            // 1/sqrt(256)

DEVI u16 f2bf(float x) {
  union { float f; unsigned u; } v; v.f = x;
  unsigned r = v.u + 0x7FFFu + ((v.u >> 16) & 1u);
  return (u16)(r >> 16);
}

DEVI u32 pack2bf(float f0, float f1) {
  u32 u0 = __float_as_uint(f0) + 0x8000u;
  u32 u1 = __float_as_uint(f1) + 0x8000u;
  return __builtin_amdgcn_perm(u1, u0, 0x07060302u); // [f1.hi16 : f0.hi16]
}

// ---- kernel 0: W_Q|W_K|W_V (each 256x1024 fp32) -> Wb[768][1024] bf16 ----
__global__ void cvt_w_kernel(const float4* __restrict__ wq, const float4* __restrict__ wk,
                             const float4* __restrict__ wv, u16x4* __restrict__ dst) {
  int i = blockIdx.x * blockDim.x + threadIdx.x; // 0..196607
  int w = i >> 16, off = i & 65535;
  const float4* s = (w == 0) ? wq : ((w == 1) ? wk : wv);
  float4 v = s[off];
  u16x4 o; o.x = f2bf(v.x); o.y = f2bf(v.y); o.z = f2bf(v.z); o.w = f2bf(v.w);
  dst[(w << 16) + off] = o;
}

// ---- kernel 1: fused QKV GEMM  C[16384x768] = x[16384x1024](fp32)*Wb^T ---
// 128x128 tile, BK=32, 4 waves, grid 768 = 3 WG/CU (cross-WG overlap).
// Reg-staged BOTH operands (T14 issue-early/write-late): A fp32 loads with
// fused cvt->bf16; B bf16 loads. PADDED LDS rows (40 u16 = 80 B, 16B-aligned)
// -> bank = (20*row + 4*slot) mod 32: frag reads exactly 2-way (free),
// no XOR swizzle to get wrong. Raw s_barrier + lgkmcnt(0)-only waits so the
// t+1 global loads stay in flight across barriers; ds_writes self-wait via
// compiler per-register vmcnt.
__global__ __launch_bounds__(256, 3) void qkv_gemm_kernel(const float* __restrict__ Xf, const u16* __restrict__ Wb,
                                                          u16* __restrict__ Qb, u16* __restrict__ Kb,
                                                          u16* __restrict__ Vt) {
  __shared__ u16 Asw[128 * 40];   // 10240 B
  __shared__ u16 Bsw[128 * 40];   // 10240 B
  const int lin = blockIdx.x;                     // 0..767
  const int rl = (lin & 7) * 96 + (lin >> 3);     // XCD-chunked bijection
  const int nt = rl % 6;
  const int m0 = (rl / 6) * 128;
  const int n0 = nt * 128;
  const int tid = threadIdx.x;
  const int wid = tid >> 6, lane = tid & 63;
  const int wm = wid >> 1, wn = wid & 1;
  const int lrow = lane & 15, lkg = lane >> 4;

  // A staging map: granule g = r*256+tid (r 0..3): row = r*32 + (tid>>3), 16B fp32 slot = tid&7
  const int a_row = tid >> 3, a_slot = tid & 7;
  const float* a_g = Xf + (size_t)(m0 + a_row) * 1024 + a_slot * 4;
  const int a_w = a_row * 40 + a_slot * 4;        // u16 idx (byte 8-aligned for b64 write)
  // B staging map: granule g = r*256+tid (r 0..1): row = r*64 + (tid>>2), 16B slot = tid&3
  const int b_row = tid >> 2, b_slot = tid & 3;
  const u16* b_g = Wb + (size_t)(n0 + b_row) * 1024 + b_slot * 8;
  const int b_w = b_row * 40 + b_slot * 8;        // byte 16-aligned

  float4 arg[4];
  uint4 brg[2];

#define GISSUE(T) do { \
  _Pragma("unroll") for (int r_ = 0; r_ < 4; ++r_) \
    arg[r_] = *(const float4*)(a_g + (size_t)r_ * 32 * 1024 + (T) * 32); \
  _Pragma("unroll") for (int r_ = 0; r_ < 2; ++r_) \
    brg[r_] = *(const uint4*)(const void*)(b_g + (size_t)r_ * 64 * 1024 + (T) * 32); \
} while (0)

#define SWRITE() do { \
  _Pragma("unroll") for (int r_ = 0; r_ < 4; ++r_) { \
    uint2 pk_; pk_.x = pack2bf(arg[r_].x, arg[r_].y); pk_.y = pack2bf(arg[r_].z, arg[r_].w); \
    *(uint2*)&Asw[r_ * 32 * 40 + a_w] = pk_; } \
  _Pragma("unroll") for (int r_ = 0; r_ < 2; ++r_) \
    *(uint4*)&Bsw[r_ * 64 * 40 + b_w] = brg[r_]; \
} while (0)

  f32x4 acc[4][4] = {};

  // ---- prologue: tile 0 ----
  GISSUE(0);
  SWRITE();                                        // auto vmcnt waits on arg/brg
  asm volatile("s_waitcnt lgkmcnt(0)" ::: "memory");
  __builtin_amdgcn_s_barrier();
  __builtin_amdgcn_sched_barrier(0);

  for (int kt = 0; kt < 32; ++kt) {
    if (kt < 31) GISSUE(kt + 1);                   // issue-early (T14)
    __builtin_amdgcn_sched_barrier(0);
    bf16x8 a[4], b[4];
#pragma unroll
    for (int mf = 0; mf < 4; ++mf) a[mf] = *(const bf16x8*)&Asw[(wm * 64 + mf * 16 + lrow) * 40 + lkg * 8];
#pragma unroll
    for (int nf = 0; nf < 4; ++nf) b[nf] = *(const bf16x8*)&Bsw[(wn * 64 + nf * 16 + lrow) * 40 + lkg * 8];
    __builtin_amdgcn_s_setprio(1);
#pragma unroll
    for (int mf = 0; mf < 4; ++mf)
#pragma unroll
      for (int nf = 0; nf < 4; ++nf)
        acc[mf][nf] = __builtin_amdgcn_mfma_f32_16x16x32_bf16(a[mf], b[nf], acc[mf][nf], 0, 0, 0);
    __builtin_amdgcn_s_setprio(0);
    asm volatile("s_waitcnt lgkmcnt(0)" ::: "memory");
    __builtin_amdgcn_s_barrier();                  // all reads of tile kt done
    __builtin_amdgcn_sched_barrier(0);
    if (kt < 31) {
      SWRITE();                                    // write-late (waits only its regs)
      asm volatile("s_waitcnt lgkmcnt(0)" ::: "memory");
      __builtin_amdgcn_s_barrier();                // tile kt+1 visible
      __builtin_amdgcn_sched_barrier(0);
    }
  }

  // ---- epilogue: nt 0,1 -> Q; 2,3 -> K; 4,5 -> V transposed ----
  const int rbase = lkg * 4;
  if (nt < 4) {
    u16* Dst = (nt < 2) ? Qb : Kb;
    const int cb = (nt < 2) ? n0 : (n0 - 256);
#pragma unroll
    for (int mf = 0; mf < 4; ++mf)
#pragma unroll
      for (int nf = 0; nf < 4; ++nf) {
        const int gm = m0 + wm * 64 + mf * 16 + rbase;
        const int c = cb + wn * 64 + nf * 16 + lrow;
#pragma unroll
        for (int r = 0; r < 4; ++r) Dst[(size_t)(gm + r) * 256 + c] = f2bf(acc[mf][nf][r]);
      }
  } else {
#pragma unroll
    for (int mf = 0; mf < 4; ++mf)
#pragma unroll
      for (int nf = 0; nf < 4; ++nf) {
        const int gm = m0 + wm * 64 + mf * 16 + rbase;
        const int h = n0 - 512 + wn * 64 + nf * 16 + lrow;
        const int bb = gm >> 12, l = gm & 4095;
        u16x4 pk;
        pk.x = f2bf(acc[mf][nf][0]); pk.y = f2bf(acc[mf][nf][1]);
        pk.z = f2bf(acc[mf][nf][2]); pk.w = f2bf(acc[mf][nf][3]);
        *(u16x4*)&Vt[((size_t)bb * 256 + h) * 4096 + l] = pk;
      }
  }
}

// ---- kernel 2: WINDOWED decay attention ----------------------------------
// gamma^320 ~ 2.5e-15 => keys older than the aligned 256..319 window are
// numerically zero in fp32. QB=32 rows/WG, KB=64, 4 waves (256 thr).
__global__ __launch_bounds__(256) void attn_kernel(const u16* __restrict__ Qb, const u16* __restrict__ Kb,
                                                   const u16* __restrict__ Vt, float* __restrict__ out) {
  __shared__ u16 Plds[32 * 72];
  const int raw = blockIdx.x;                 // 0..511
  const int aid = (raw & 7) * 64 + (raw >> 3);  // XCD-chunked
  const int b = aid >> 7;                     // 0..3
  const int qt = aid & 127;                   // 0..127
  const int qb = qt * 32;
  const int tid = threadIdx.x;
  const int wid = tid >> 6, lane = tid & 63;
  const int lrow = lane & 15, lkg = lane >> 4, lk = lkg * 8;
  const size_t bQK = (size_t)b * 4096 * 256;

  bf16x8 qf[2][8];
#pragma unroll
  for (int mf = 0; mf < 2; ++mf) {
    const u16* Qrow = Qb + bQK + (size_t)(qb + mf * 16 + lrow) * 256;
#pragma unroll
    for (int kf = 0; kf < 8; ++kf) qf[mf][kf] = *(const bf16x8*)&Qrow[kf * 32 + lk];
  }

  int kstart = qb - 256; if (kstart < 0) kstart = 0; kstart &= ~63;
  const int njt = (qb + 32 - kstart + 63) >> 6;

  f32x4 oacc[2][4] = {};

  for (int jt = 0; jt < njt; ++jt) {
    const int kb = kstart + jt * 64;
    f32x4 s[2] = {};
    const u16* Krow = Kb + bQK + (size_t)(kb + wid * 16 + lrow) * 256;
#pragma unroll
    for (int kf = 0; kf < 8; ++kf) {
      const bf16x8 kfr = *(const bf16x8*)&Krow[kf * 32 + lk];
      s[0] = __builtin_amdgcn_mfma_f32_16x16x32_bf16(qf[0][kf], kfr, s[0], 0, 0, 0);
      s[1] = __builtin_amdgcn_mfma_f32_16x16x32_bf16(qf[1][kf], kfr, s[1], 0, 0, 0);
    }
    const int kg = kb + wid * 16 + lrow;
#pragma unroll
    for (int mf = 0; mf < 2; ++mf) {
      const int qg = qb + mf * 16 + lkg * 4;
#pragma unroll
      for (int r = 0; r < 4; ++r) {
        const int d = qg + r - kg;
        const float pv = (d >= 0) ? s[mf][r] * exp2f((float)d * L2GAMMA) * INV_SQRT_H : 0.0f;
        Plds[(mf * 16 + lkg * 4 + r) * 72 + wid * 16 + lrow] = f2bf(pv);
      }
    }
    __syncthreads();
#pragma unroll
    for (int ks = 0; ks < 2; ++ks) {
      bf16x8 pa[2];
      pa[0] = *(const bf16x8*)&Plds[(lrow) * 72 + ks * 32 + lk];
      pa[1] = *(const bf16x8*)&Plds[(16 + lrow) * 72 + ks * 32 + lk];
#pragma unroll
      for (int nf = 0; nf < 4; ++nf) {
        const bf16x8 vb = *(const bf16x8*)&Vt[((size_t)b * 256 + wid * 64 + nf * 16 + lrow) * 4096 + kb + ks * 32 + lk];
        oacc[0][nf] = __builtin_amdgcn_mfma_f32_16x16x32_bf16(pa[0], vb, oacc[0][nf], 0, 0, 0);
        oacc[1][nf] = __builtin_amdgcn_mfma_f32_16x16x32_bf16(pa[1], vb, oacc[1][nf], 0, 0, 0);
      }
    }
    __syncthreads();
  }

#pragma unroll
  for (int mf = 0; mf < 2; ++mf) {
    float* obase = out + ((size_t)b * 4096 + qb + mf * 16 + lkg * 4) * 256 + wid * 64 + lrow;
#pragma unroll
    for (int nf = 0; nf < 4; ++nf)
#pragma unroll
      for (int r = 0; r < 4; ++r)
        obase[(size_t)r * 256 + nf * 16] = oacc[mf][nf][r];
  }
}

extern "C" void kernel_launch(void* const* d_in, const int* in_sizes, int n_in,
                              void* d_out, int out_size, void* d_ws, size_t ws_size,
                              hipStream_t stream) {
  const float* x  = (const float*)d_in[0];
  const float* wq = (const float*)d_in[1];
  const float* wk = (const float*)d_in[2];
  const float* wv = (const float*)d_in[3];
  float* out = (float*)d_out;
  char* ws = (char*)d_ws;
  u16* Wb = (u16*)(ws);                          //   768*1024*2 = 1,572,864
  u16* Qb = (u16*)(ws + (size_t)1572864);        // 16384*256*2  = 8,388,608
  u16* Kb = (u16*)(ws + (size_t)9961472);        //  8,388,608
  u16* Vt = (u16*)(ws + (size_t)18350080);       //  8,388,608  (end 26,738,688)

  hipLaunchKernelGGL(cvt_w_kernel, dim3(768), dim3(256), 0, stream,
                     (const float4*)wq, (const float4*)wk, (const float4*)wv, (u16x4*)Wb);
  hipLaunchKernelGGL(qkv_gemm_kernel, dim3(768), dim3(256), 0, stream, x, Wb, Qb, Kb, Vt);
  hipLaunchKernelGGL(attn_kernel, dim3(512), dim3(256), 0, stream, Qb, Kb, Vt, out);
}